// Round 2
// baseline (1092.182 us; speedup 1.0000x reference)
//
#include <hip/hip_runtime.h>
#include <math.h>

#define NROWS 131072
#define DD    512
#define GG    4096

typedef __attribute__((ext_vector_type(8))) short bf16x8;   // 8 bf16 = 4 VGPRs
typedef __attribute__((ext_vector_type(4))) float f32x4;

__device__ __forceinline__ unsigned short f2b(float f) {
    unsigned u = __float_as_uint(f);
    unsigned r = (u + 0x7FFFu + ((u >> 16) & 1u)) >> 16;   // RNE
    return (unsigned short)r;
}
__device__ __forceinline__ float b2f(unsigned short h) {
    return __uint_as_float(((unsigned)h) << 16);
}

__device__ __forceinline__ void async_copy16(const void* g, void* l) {
    __builtin_amdgcn_global_load_lds(
        (const __attribute__((address_space(1))) void*)g,
        (__attribute__((address_space(3))) void*)l, 16, 0, 0);
}

// ---------------------------------------------------------------------------
// K0: fp32 -> bf16 conversion (vectorized, RNE)
// ---------------------------------------------------------------------------
__global__ __launch_bounds__(256) void k_f2b(const float* __restrict__ in,
                                             unsigned short* __restrict__ out, int n4) {
    int i = blockIdx.x * blockDim.x + threadIdx.x;
    if (i < n4) {
        float4 v = ((const float4*)in)[i];
        ushort4 o;
        o.x = f2b(v.x); o.y = f2b(v.y); o.z = f2b(v.z); o.w = f2b(v.w);
        ((ushort4*)out)[i] = o;
    }
}

// ---------------------------------------------------------------------------
// K1: histogram of group ids
// ---------------------------------------------------------------------------
__global__ void k_hist(const int* __restrict__ jx, int* __restrict__ counts, int n) {
    int i = blockIdx.x * blockDim.x + threadIdx.x;
    if (i < n) atomicAdd(&counts[jx[i]], 1);
}

// ---------------------------------------------------------------------------
// K2: exclusive scan of 4096 counts -> offsets[4097]  (single block)
// ---------------------------------------------------------------------------
__global__ __launch_bounds__(1024) void k_scan4096(const int* __restrict__ counts,
                                                   int* __restrict__ offsets) {
    __shared__ int buf[GG];
    __shared__ int part[1024];
    const int t = threadIdx.x;
    for (int i = t; i < GG; i += 1024) buf[i] = counts[i];
    __syncthreads();
    const int base = t * 4;
    int s0 = buf[base + 0];
    int s1 = s0 + buf[base + 1];
    int s2 = s1 + buf[base + 2];
    int s3 = s2 + buf[base + 3];
    part[t] = s3;
    __syncthreads();
    for (int off = 1; off < 1024; off <<= 1) {
        int v = (t >= off) ? part[t - off] : 0;
        __syncthreads();
        part[t] += v;
        __syncthreads();
    }
    int excl = (t == 0) ? 0 : part[t - 1];
    offsets[base + 0] = excl;
    offsets[base + 1] = excl + s0;
    offsets[base + 2] = excl + s1;
    offsets[base + 3] = excl + s2;
    if (t == 1023) offsets[GG] = excl + s3;
}

// ---------------------------------------------------------------------------
// K3: scatter row indices into group-sorted order[]
// ---------------------------------------------------------------------------
__global__ void k_scatter(const int* __restrict__ jx, const int* __restrict__ offsets,
                          int* __restrict__ cursor, int* __restrict__ order, int n) {
    int i = blockIdx.x * blockDim.x + threadIdx.x;
    if (i < n) {
        int g = jx[i];
        int p = atomicAdd(&cursor[g], 1);
        order[offsets[g] + p] = i;
    }
}

// ---------------------------------------------------------------------------
// K4: bf16 MFMA dual GEMM.  C1 = A@B1^T + bias1, C2 = A@B2^T + bias2.
//     A:[M,512] bf16 row-major; B1,B2:[512,512] bf16 row-major.
//     128x128 tile, BK=64, 256 threads (4 waves, 2x2), each wave 64x64 per
//     output, 4x4 grid of 16x16x32 MFMA over two k sub-steps.
//     LDS tiles stored K-CHUNK-MAJOR [BK/8][128][8] so fragment ds_read_b128
//     is bank-conflict-free (bank-group = row%8, 2 lanes/group) while the
//     global_load_lds destination stays LINEAR (chunk id = j*256 + tid):
//     only the per-lane GLOBAL source address is permuted, which is allowed.
// ---------------------------------------------------------------------------
__global__ __launch_bounds__(256) void k_dual_gemm_mfma(
    const unsigned short* __restrict__ A,
    const unsigned short* __restrict__ B1, const float* __restrict__ bias1,
    const unsigned short* __restrict__ B2, const float* __restrict__ bias2,
    unsigned short* __restrict__ C1, unsigned short* __restrict__ C2)
{
    // [8][128][8] shorts each = 16 KB; 3 tiles = 48 KB LDS
    __shared__ short sA [8192];
    __shared__ short sB1[8192];
    __shared__ short sB2[8192];

    const int t  = threadIdx.x;
    const int w  = t >> 6;        // wave 0..3
    const int L  = t & 63;        // lane
    const int wr = w >> 1;        // wave row (0..1)
    const int wc = w & 1;         // wave col (0..1)
    const int lane15 = L & 15;
    const int q  = L >> 4;        // quad 0..3

    const int m0 = blockIdx.y << 7;   // row tile base
    const int d0 = blockIdx.x << 7;   // col tile base

    f32x4 acc1[4][4], acc2[4][4];
    const f32x4 z = {0.f, 0.f, 0.f, 0.f};
    #pragma unroll
    for (int i = 0; i < 4; ++i)
        #pragma unroll
        for (int j = 0; j < 4; ++j) { acc1[i][j] = z; acc2[i][j] = z; }

    // Staging decomposition: 1024 16B-chunks per tile; iteration j covers
    // chunk = j*256 + t.  row = chunk & 127, q8 = chunk >> 7.
    // LDS dest (j*256 + w*64)*16 B is wave-uniform; lane L lands at +L*16,
    // i.e. exactly chunk (j*256+t) -- matches its own global source.
    size_t offA[4], offB[4];
    int ldsoff[4];                      // in shorts
    #pragma unroll
    for (int j = 0; j < 4; ++j) {
        const int chunk = (j << 8) + t;
        const int row   = chunk & 127;
        const int q8    = chunk >> 7;
        offA[j]   = (size_t)(m0 + row) * DD + (q8 << 3);
        offB[j]   = (size_t)(d0 + row) * DD + (q8 << 3);
        ldsoff[j] = ((j << 8) + (w << 6)) << 3;
    }

    for (int k0 = 0; k0 < DD; k0 += 64) {
        // ---- async stage 128x64 tiles of A, B1, B2 (K-chunk-major layout)
        #pragma unroll
        for (int j = 0; j < 4; ++j) {
            async_copy16(A  + offA[j] + k0, &sA [ldsoff[j]]);
            async_copy16(B1 + offB[j] + k0, &sB1[ldsoff[j]]);
            async_copy16(B2 + offB[j] + k0, &sB2[ldsoff[j]]);
        }
        __syncthreads();   // drains vmcnt -> LDS visible

        // ---- two k sub-steps of 32; k ascends k0, k0+32 (order identical
        //      to BK=32 version -> bit-identical accumulation)
        #pragma unroll
        for (int kk = 0; kk < 2; ++kk) {
            bf16x8 aF[4], bF1[4], bF2[4];
            const int kbase = ((kk << 2) + q) << 10;   // q8 * 1024 shorts
            #pragma unroll
            for (int i = 0; i < 4; ++i) {
                const int rA = (wr << 6) + (i << 4) + lane15;
                aF[i] = *(const bf16x8*)&sA[kbase + (rA << 3)];
            }
            #pragma unroll
            for (int j = 0; j < 4; ++j) {
                const int rB = (wc << 6) + (j << 4) + lane15;
                const int o  = kbase + (rB << 3);
                bF1[j] = *(const bf16x8*)&sB1[o];
                bF2[j] = *(const bf16x8*)&sB2[o];
            }
            #pragma unroll
            for (int i = 0; i < 4; ++i)
                #pragma unroll
                for (int j = 0; j < 4; ++j) {
                    acc1[i][j] = __builtin_amdgcn_mfma_f32_16x16x32_bf16(aF[i], bF1[j], acc1[i][j], 0, 0, 0);
                    acc2[i][j] = __builtin_amdgcn_mfma_f32_16x16x32_bf16(aF[i], bF2[j], acc2[i][j], 0, 0, 0);
                }
        }
        __syncthreads();   // protect LDS before next overwrite
    }

    // ---- epilogue: C/D layout col=lane&15, row=q*4+reg
    #pragma unroll
    for (int j = 0; j < 4; ++j) {
        const int col = d0 + (wc << 6) + (j << 4) + lane15;
        const float b1 = bias1[col];
        const float b2 = bias2[col];
        #pragma unroll
        for (int i = 0; i < 4; ++i) {
            const int row0 = m0 + (wr << 6) + (i << 4) + (q << 2);
            #pragma unroll
            for (int r = 0; r < 4; ++r) {
                C1[(size_t)(row0 + r) * DD + col] = f2b(acc1[i][j][r] + b1);
                C2[(size_t)(row0 + r) * DD + col] = f2b(acc2[i][j][r] + b2);
            }
        }
    }
}

// ---------------------------------------------------------------------------
// K5: single fp32 GEMM  C = A @ B^T + bias   (y @ Wh^T, small)
// ---------------------------------------------------------------------------
__global__ __launch_bounds__(256) void k_gemm_bt(
    const float* __restrict__ A,
    const float* __restrict__ B1, const float* __restrict__ bias1,
    float* __restrict__ C1)
{
    __shared__ __align__(16) float sA[16][68];
    __shared__ __align__(16) float s1[16][68];

    const int t  = threadIdx.x;
    const int tx = t & 15;
    const int ty = t >> 4;
    const int m0 = blockIdx.y << 6;
    const int d0 = blockIdx.x << 6;
    const int lr = t >> 2;
    const int lk = (t & 3) << 2;

    float acc1[4][4] = {{0.f}};

    const float* pA = A  + (size_t)(m0 + lr) * DD + lk;
    const float* p1 = B1 + (size_t)(d0 + lr) * DD + lk;

    for (int k0 = 0; k0 < DD; k0 += 16) {
        float4 av = *(const float4*)(pA + k0);
        float4 v1 = *(const float4*)(p1 + k0);
        sA[lk+0][lr]=av.x; sA[lk+1][lr]=av.y; sA[lk+2][lr]=av.z; sA[lk+3][lr]=av.w;
        s1[lk+0][lr]=v1.x; s1[lk+1][lr]=v1.y; s1[lk+2][lr]=v1.z; s1[lk+3][lr]=v1.w;
        __syncthreads();
        #pragma unroll
        for (int kk = 0; kk < 16; ++kk) {
            float4 a = *(const float4*)&sA[kk][ty << 2];
            float4 u = *(const float4*)&s1[kk][tx << 2];
            float aa[4] = {a.x, a.y, a.z, a.w};
            float uu[4] = {u.x, u.y, u.z, u.w};
            #pragma unroll
            for (int i = 0; i < 4; ++i)
                #pragma unroll
                for (int j = 0; j < 4; ++j)
                    acc1[i][j] = fmaf(aa[i], uu[j], acc1[i][j]);
        }
        __syncthreads();
    }

    const int dcol = d0 + (tx << 2);
    float4 b1v = *(const float4*)&bias1[dcol];
    #pragma unroll
    for (int i = 0; i < 4; ++i) {
        int m = m0 + (ty << 2) + i;
        float4 r1;
        r1.x = acc1[i][0] + b1v.x; r1.y = acc1[i][1] + b1v.y;
        r1.z = acc1[i][2] + b1v.z; r1.w = acc1[i][3] + b1v.w;
        *(float4*)&C1[(size_t)m * DD + dcol] = r1;
    }
}

// ---------------------------------------------------------------------------
// K6: per-group fused softmax-weighted aggregation (single pass, bf16 in).
//     No max-shift: |logits| <= ~3, exp is safe; shift cancels exactly.
// ---------------------------------------------------------------------------
__global__ __launch_bounds__(512) void k_group_agg(
    const unsigned short* __restrict__ logits, const unsigned short* __restrict__ feats,
    const int* __restrict__ order, const int* __restrict__ offsets,
    float* __restrict__ y)
{
    const int g = blockIdx.x;
    const int d = threadIdx.x;
    const int beg = offsets[g];
    const int end = offsets[g + 1];
    if (beg == end) { y[(size_t)g * DD + d] = 0.f; return; }

    float s = 0.f, acc = 0.f;
    for (int i = beg; i < end; ++i) {
        int n = order[i];
        float e = __expf(b2f(logits[(size_t)n * DD + d]));
        float f = b2f(feats[(size_t)n * DD + d]);
        s += e;
        acc = fmaf(f, e, acc);
    }
    y[(size_t)g * DD + d] = acc / (s + 1e-12f);
}

// ---------------------------------------------------------------------------
// K7: gather out[n,:] = out_group[jx[n],:]  (flat: 1 float4 per thread)
// ---------------------------------------------------------------------------
__global__ __launch_bounds__(256) void k_gather(
    const float* __restrict__ outg, const int* __restrict__ jx,
    float* __restrict__ out)
{
    const int i  = blockIdx.x * 256 + threadIdx.x;   // over N * 128 float4s
    const int n  = i >> 7;
    const int d4 = i & 127;
    const int g  = jx[n];
    ((float4*)out)[i] = ((const float4*)outg)[(size_t)g * (DD / 4) + d4];
}

// ---------------------------------------------------------------------------
extern "C" void kernel_launch(void* const* d_in, const int* in_sizes, int n_in,
                              void* d_out, int out_size, void* d_ws, size_t ws_size,
                              hipStream_t stream)
{
    const float* x  = (const float*)d_in[0];
    const float* Wf = (const float*)d_in[1];
    const float* bf = (const float*)d_in[2];
    const float* Wg = (const float*)d_in[3];
    const float* bg = (const float*)d_in[4];
    const float* Wh = (const float*)d_in[5];
    const float* bh = (const float*)d_in[6];
    const int*   jx = (const int*)d_in[7];
    float* out = (float*)d_out;
    const int N = in_sizes[7];   // 131072

    // Workspace layout (~420 MB)
    char* ws = (char*)d_ws;
    const size_t ND2 = (size_t)N * DD * sizeof(unsigned short);   // 134 MB
    const size_t WD2 = (size_t)DD * DD * sizeof(unsigned short);  // 0.5 MB
    const size_t GD4 = (size_t)GG * DD * sizeof(float);           // 8 MB
    size_t off = 0;
    unsigned short* xb      = (unsigned short*)(ws + off); off += ND2;
    unsigned short* logitsb = (unsigned short*)(ws + off); off += ND2;
    unsigned short* featsb  = (unsigned short*)(ws + off); off += ND2;
    unsigned short* Wgb     = (unsigned short*)(ws + off); off += WD2;
    unsigned short* Wfb     = (unsigned short*)(ws + off); off += WD2;
    float* yv   = (float*)(ws + off); off += GD4;
    float* outg = (float*)(ws + off); off += GD4;
    int* counts  = (int*)(ws + off); off += (size_t)GG * 4;
    int* offsets = (int*)(ws + off); off += (size_t)(GG + 4) * 4;
    int* cursor  = (int*)(ws + off); off += (size_t)GG * 4;
    int* order   = (int*)(ws + off); off += (size_t)N * 4;

    hipMemsetAsync(counts, 0, (size_t)GG * 4, stream);
    hipMemsetAsync(cursor, 0, (size_t)GG * 4, stream);

    // Group-sort bookkeeping
    k_hist<<<N / 256, 256, 0, stream>>>(jx, counts, N);
    k_scan4096<<<1, 1024, 0, stream>>>(counts, offsets);
    k_scatter<<<N / 256, 256, 0, stream>>>(jx, offsets, cursor, order, N);

    // fp32 -> bf16 conversions
    k_f2b<<<(N * (DD / 4)) / 256, 256, 0, stream>>>(x, xb, N * (DD / 4));
    k_f2b<<<(DD * DD / 4) / 256, 256, 0, stream>>>(Wg, Wgb, DD * DD / 4);
    k_f2b<<<(DD * DD / 4) / 256, 256, 0, stream>>>(Wf, Wfb, DD * DD / 4);

    // logits = x@Wg^T + bg ; feats = x@Wf^T + bf   (bf16 MFMA, bf16 out)
    k_dual_gemm_mfma<<<dim3(DD / 128, N / 128), 256, 0, stream>>>(
        xb, Wgb, bg, Wfb, bf, logitsb, featsb);

    // per-group softmax-weighted sum (fp32 accumulate)
    k_group_agg<<<GG, 512, 0, stream>>>(logitsb, featsb, order, offsets, yv);

    // out_group = y@Wh^T + bh  (fp32, small)
    k_gemm_bt<<<dim3(DD / 64, GG / 64), 256, 0, stream>>>(yv, Wh, bh, outg);

    // out = out_group[jx]
    k_gather<<<(N * (DD / 4)) / 256, 256, 0, stream>>>(outg, jx, out);
}

// Round 3
// 917.715 us; speedup vs baseline: 1.1901x; 1.1901x over previous
//
#include <hip/hip_runtime.h>
#include <math.h>

#define NROWS 131072
#define DD    512
#define GG    4096

typedef __attribute__((ext_vector_type(8))) short bf16x8;   // 8 bf16 = 4 VGPRs
typedef __attribute__((ext_vector_type(4))) float f32x4;

__device__ __forceinline__ unsigned short f2b(float f) {
    unsigned u = __float_as_uint(f);
    unsigned r = (u + 0x7FFFu + ((u >> 16) & 1u)) >> 16;   // RNE
    return (unsigned short)r;
}
__device__ __forceinline__ float b2f(unsigned short h) {
    return __uint_as_float(((unsigned)h) << 16);
}

__device__ __forceinline__ void async_copy16(const void* g, void* l) {
    __builtin_amdgcn_global_load_lds(
        (const __attribute__((address_space(1))) void*)g,
        (__attribute__((address_space(3))) void*)l, 16, 0, 0);
}

// ---------------------------------------------------------------------------
// K0: fp32 -> bf16 conversion (vectorized, RNE)
// ---------------------------------------------------------------------------
__global__ __launch_bounds__(256) void k_f2b(const float* __restrict__ in,
                                             unsigned short* __restrict__ out, int n4) {
    int i = blockIdx.x * blockDim.x + threadIdx.x;
    if (i < n4) {
        float4 v = ((const float4*)in)[i];
        ushort4 o;
        o.x = f2b(v.x); o.y = f2b(v.y); o.z = f2b(v.z); o.w = f2b(v.w);
        ((ushort4*)out)[i] = o;
    }
}

// ---------------------------------------------------------------------------
// K1: histogram of group ids
// ---------------------------------------------------------------------------
__global__ void k_hist(const int* __restrict__ jx, int* __restrict__ counts, int n) {
    int i = blockIdx.x * blockDim.x + threadIdx.x;
    if (i < n) atomicAdd(&counts[jx[i]], 1);
}

// ---------------------------------------------------------------------------
// K2: exclusive scan of 4096 counts -> offsets[4097]  (single block)
// ---------------------------------------------------------------------------
__global__ __launch_bounds__(1024) void k_scan4096(const int* __restrict__ counts,
                                                   int* __restrict__ offsets) {
    __shared__ int buf[GG];
    __shared__ int part[1024];
    const int t = threadIdx.x;
    for (int i = t; i < GG; i += 1024) buf[i] = counts[i];
    __syncthreads();
    const int base = t * 4;
    int s0 = buf[base + 0];
    int s1 = s0 + buf[base + 1];
    int s2 = s1 + buf[base + 2];
    int s3 = s2 + buf[base + 3];
    part[t] = s3;
    __syncthreads();
    for (int off = 1; off < 1024; off <<= 1) {
        int v = (t >= off) ? part[t - off] : 0;
        __syncthreads();
        part[t] += v;
        __syncthreads();
    }
    int excl = (t == 0) ? 0 : part[t - 1];
    offsets[base + 0] = excl;
    offsets[base + 1] = excl + s0;
    offsets[base + 2] = excl + s1;
    offsets[base + 3] = excl + s2;
    if (t == 1023) offsets[GG] = excl + s3;
}

// ---------------------------------------------------------------------------
// K3: scatter row indices into group-sorted order[]
// ---------------------------------------------------------------------------
__global__ void k_scatter(const int* __restrict__ jx, const int* __restrict__ offsets,
                          int* __restrict__ cursor, int* __restrict__ order, int n) {
    int i = blockIdx.x * blockDim.x + threadIdx.x;
    if (i < n) {
        int g = jx[i];
        int p = atomicAdd(&cursor[g], 1);
        order[offsets[g] + p] = i;
    }
}

// ---------------------------------------------------------------------------
// K4: bf16 MFMA dual GEMM.  C1 = A@B1^T + bias1, C2 = A@B2^T + bias2.
//     128x128 tile, BK=32, 256 threads (4 waves 2x2), DOUBLE-BUFFERED LDS:
//       stage(buf^1, t+1) issued BEFORE compute(buf, t); single barrier per
//       K-step -> the __syncthreads vmcnt(0) drain lands after the MFMA
//       phase, hiding most of the global_load_lds latency (T3 minimum).
//     LDS tiles K-CHUNK-MAJOR [4][128][8]: fragment ds_read_b128 is
//     bank-conflict-free (verified: SQ_LDS_BANK_CONFLICT = 0) while the
//     global_load_lds destination stays LINEAR (only the per-lane GLOBAL
//     source address is permuted, which is allowed).
//     Grid flattened 1-D with chunked XCD swizzle: the 4 col-tiles sharing
//     an A-panel run on the same XCD -> A re-reads hit that XCD's L2.
// ---------------------------------------------------------------------------
__global__ __launch_bounds__(256) void k_dual_gemm_mfma(
    const unsigned short* __restrict__ A,
    const unsigned short* __restrict__ B1, const float* __restrict__ bias1,
    const unsigned short* __restrict__ B2, const float* __restrict__ bias2,
    unsigned short* __restrict__ C1, unsigned short* __restrict__ C2)
{
    // [buf][tile A/B1/B2][4096 shorts = 8KB] -> 48 KB total
    __shared__ short lds[2][3][4096];

    const int t  = threadIdx.x;
    const int w  = t >> 6;        // wave 0..3
    const int L  = t & 63;        // lane
    const int wr = w >> 1;        // wave row (0..1)
    const int wc = w & 1;         // wave col (0..1)
    const int lane15 = L & 15;
    const int q  = L >> 4;        // quad 0..3

    // chunked XCD swizzle over 4096 blocks (bijective: 4096 % 8 == 0)
    const int hw      = blockIdx.x;
    const int logical = ((hw & 7) << 9) + (hw >> 3);
    const int m0 = (logical >> 2) << 7;   // row tile base (1024 tiles)
    const int d0 = (logical & 3) << 7;    // col tile base (4 tiles)

    f32x4 acc1[4][4], acc2[4][4];
    const f32x4 z = {0.f, 0.f, 0.f, 0.f};
    #pragma unroll
    for (int i = 0; i < 4; ++i)
        #pragma unroll
        for (int j = 0; j < 4; ++j) { acc1[i][j] = z; acc2[i][j] = z; }

    // Staging: 512 16B-chunks per tile, 2 iterations (chunk = j*256 + t).
    // row = chunk & 127, q8 = chunk >> 7.  LDS dest wave-uniform + lane*16.
    size_t offA[2], offB[2];
    int ldsoff[2];                      // in shorts
    #pragma unroll
    for (int j = 0; j < 2; ++j) {
        const int chunk = (j << 8) + t;
        const int row   = chunk & 127;
        const int q8    = chunk >> 7;
        offA[j]   = (size_t)(m0 + row) * DD + (q8 << 3);
        offB[j]   = (size_t)(d0 + row) * DD + (q8 << 3);
        ldsoff[j] = ((j << 8) + (w << 6)) << 3;
    }

    auto stage = [&](int buf, int k0) {
        #pragma unroll
        for (int j = 0; j < 2; ++j) {
            async_copy16(A  + offA[j] + k0, &lds[buf][0][ldsoff[j]]);
            async_copy16(B1 + offB[j] + k0, &lds[buf][1][ldsoff[j]]);
            async_copy16(B2 + offB[j] + k0, &lds[buf][2][ldsoff[j]]);
        }
    };

    auto compute = [&](int cur) {
        const short* pA  = &lds[cur][0][0];
        const short* pB1 = &lds[cur][1][0];
        const short* pB2 = &lds[cur][2][0];
        bf16x8 aF[4], bF1[4], bF2[4];
        const int kbase = q << 10;      // q8 = q: 4 k-chunks of 8
        #pragma unroll
        for (int i = 0; i < 4; ++i)
            aF[i] = *(const bf16x8*)&pA[kbase + (((wr << 6) + (i << 4) + lane15) << 3)];
        #pragma unroll
        for (int j = 0; j < 4; ++j) {
            const int o = kbase + (((wc << 6) + (j << 4) + lane15) << 3);
            bF1[j] = *(const bf16x8*)&pB1[o];
            bF2[j] = *(const bf16x8*)&pB2[o];
        }
        #pragma unroll
        for (int i = 0; i < 4; ++i)
            #pragma unroll
            for (int j = 0; j < 4; ++j) {
                acc1[i][j] = __builtin_amdgcn_mfma_f32_16x16x32_bf16(aF[i], bF1[j], acc1[i][j], 0, 0, 0);
                acc2[i][j] = __builtin_amdgcn_mfma_f32_16x16x32_bf16(aF[i], bF2[j], acc2[i][j], 0, 0, 0);
            }
    };

    // prologue
    stage(0, 0);
    __syncthreads();
    // steady state: prefetch next K-tile, compute current, one barrier/step.
    for (int ks = 0; ks < 15; ++ks) {
        stage((ks + 1) & 1, (ks + 1) << 5);
        compute(ks & 1);
        __syncthreads();   // drains vmcnt -> next buffer ready; LDS reads done
    }
    compute(1);            // ks = 15 (k ascending throughout -> bit-identical)

    // ---- epilogue: C/D layout col=lane&15, row=q*4+reg
    #pragma unroll
    for (int j = 0; j < 4; ++j) {
        const int col = d0 + (wc << 6) + (j << 4) + lane15;
        const float b1 = bias1[col];
        const float b2 = bias2[col];
        #pragma unroll
        for (int i = 0; i < 4; ++i) {
            const int row0 = m0 + (wr << 6) + (i << 4) + (q << 2);
            #pragma unroll
            for (int r = 0; r < 4; ++r) {
                C1[(size_t)(row0 + r) * DD + col] = f2b(acc1[i][j][r] + b1);
                C2[(size_t)(row0 + r) * DD + col] = f2b(acc2[i][j][r] + b2);
            }
        }
    }
}

// ---------------------------------------------------------------------------
// K5: single fp32 GEMM  C = A @ B^T + bias   (y @ Wh^T, small)
// ---------------------------------------------------------------------------
__global__ __launch_bounds__(256) void k_gemm_bt(
    const float* __restrict__ A,
    const float* __restrict__ B1, const float* __restrict__ bias1,
    float* __restrict__ C1)
{
    __shared__ __align__(16) float sA[16][68];
    __shared__ __align__(16) float s1[16][68];

    const int t  = threadIdx.x;
    const int tx = t & 15;
    const int ty = t >> 4;
    const int m0 = blockIdx.y << 6;
    const int d0 = blockIdx.x << 6;
    const int lr = t >> 2;
    const int lk = (t & 3) << 2;

    float acc1[4][4] = {{0.f}};

    const float* pA = A  + (size_t)(m0 + lr) * DD + lk;
    const float* p1 = B1 + (size_t)(d0 + lr) * DD + lk;

    for (int k0 = 0; k0 < DD; k0 += 16) {
        float4 av = *(const float4*)(pA + k0);
        float4 v1 = *(const float4*)(p1 + k0);
        sA[lk+0][lr]=av.x; sA[lk+1][lr]=av.y; sA[lk+2][lr]=av.z; sA[lk+3][lr]=av.w;
        s1[lk+0][lr]=v1.x; s1[lk+1][lr]=v1.y; s1[lk+2][lr]=v1.z; s1[lk+3][lr]=v1.w;
        __syncthreads();
        #pragma unroll
        for (int kk = 0; kk < 16; ++kk) {
            float4 a = *(const float4*)&sA[kk][ty << 2];
            float4 u = *(const float4*)&s1[kk][tx << 2];
            float aa[4] = {a.x, a.y, a.z, a.w};
            float uu[4] = {u.x, u.y, u.z, u.w};
            #pragma unroll
            for (int i = 0; i < 4; ++i)
                #pragma unroll
                for (int j = 0; j < 4; ++j)
                    acc1[i][j] = fmaf(aa[i], uu[j], acc1[i][j]);
        }
        __syncthreads();
    }

    const int dcol = d0 + (tx << 2);
    float4 b1v = *(const float4*)&bias1[dcol];
    #pragma unroll
    for (int i = 0; i < 4; ++i) {
        int m = m0 + (ty << 2) + i;
        float4 r1;
        r1.x = acc1[i][0] + b1v.x; r1.y = acc1[i][1] + b1v.y;
        r1.z = acc1[i][2] + b1v.z; r1.w = acc1[i][3] + b1v.w;
        *(float4*)&C1[(size_t)m * DD + dcol] = r1;
    }
}

// ---------------------------------------------------------------------------
// K6: per-group fused softmax-weighted aggregation (single pass, bf16 in).
//     4-way unrolled: 4 independent row streams per iteration -> 4x the
//     memory-level parallelism (the serial order[i]->row-load chain was
//     latency-bound).  No max-shift: |logits| small, exp safe.
// ---------------------------------------------------------------------------
__global__ __launch_bounds__(512) void k_group_agg(
    const unsigned short* __restrict__ logits, const unsigned short* __restrict__ feats,
    const int* __restrict__ order, const int* __restrict__ offsets,
    float* __restrict__ y)
{
    const int g = blockIdx.x;
    const int d = threadIdx.x;
    const int beg = offsets[g];
    const int end = offsets[g + 1];
    if (beg == end) { y[(size_t)g * DD + d] = 0.f; return; }

    float s = 0.f, acc = 0.f;
    int i = beg;
    for (; i + 4 <= end; i += 4) {
        const int n0 = order[i + 0];
        const int n1 = order[i + 1];
        const int n2 = order[i + 2];
        const int n3 = order[i + 3];
        const float l0 = b2f(logits[(size_t)n0 * DD + d]);
        const float l1 = b2f(logits[(size_t)n1 * DD + d]);
        const float l2 = b2f(logits[(size_t)n2 * DD + d]);
        const float l3 = b2f(logits[(size_t)n3 * DD + d]);
        const float f0 = b2f(feats[(size_t)n0 * DD + d]);
        const float f1 = b2f(feats[(size_t)n1 * DD + d]);
        const float f2 = b2f(feats[(size_t)n2 * DD + d]);
        const float f3 = b2f(feats[(size_t)n3 * DD + d]);
        const float e0 = __expf(l0);
        const float e1 = __expf(l1);
        const float e2 = __expf(l2);
        const float e3 = __expf(l3);
        s += e0; s += e1; s += e2; s += e3;
        acc = fmaf(f0, e0, acc);
        acc = fmaf(f1, e1, acc);
        acc = fmaf(f2, e2, acc);
        acc = fmaf(f3, e3, acc);
    }
    for (; i < end; ++i) {
        const int n = order[i];
        const float e = __expf(b2f(logits[(size_t)n * DD + d]));
        const float f = b2f(feats[(size_t)n * DD + d]);
        s += e;
        acc = fmaf(f, e, acc);
    }
    y[(size_t)g * DD + d] = acc / (s + 1e-12f);
}

// ---------------------------------------------------------------------------
// K7: gather out[n,:] = out_group[jx[n],:]  (flat: 1 float4 per thread)
// ---------------------------------------------------------------------------
__global__ __launch_bounds__(256) void k_gather(
    const float* __restrict__ outg, const int* __restrict__ jx,
    float* __restrict__ out)
{
    const int i  = blockIdx.x * 256 + threadIdx.x;   // over N * 128 float4s
    const int n  = i >> 7;
    const int d4 = i & 127;
    const int g  = jx[n];
    ((float4*)out)[i] = ((const float4*)outg)[(size_t)g * (DD / 4) + d4];
}

// ---------------------------------------------------------------------------
extern "C" void kernel_launch(void* const* d_in, const int* in_sizes, int n_in,
                              void* d_out, int out_size, void* d_ws, size_t ws_size,
                              hipStream_t stream)
{
    const float* x  = (const float*)d_in[0];
    const float* Wf = (const float*)d_in[1];
    const float* bf = (const float*)d_in[2];
    const float* Wg = (const float*)d_in[3];
    const float* bg = (const float*)d_in[4];
    const float* Wh = (const float*)d_in[5];
    const float* bh = (const float*)d_in[6];
    const int*   jx = (const int*)d_in[7];
    float* out = (float*)d_out;
    const int N = in_sizes[7];   // 131072

    // Workspace layout (~420 MB)
    char* ws = (char*)d_ws;
    const size_t ND2 = (size_t)N * DD * sizeof(unsigned short);   // 134 MB
    const size_t WD2 = (size_t)DD * DD * sizeof(unsigned short);  // 0.5 MB
    const size_t GD4 = (size_t)GG * DD * sizeof(float);           // 8 MB
    size_t off = 0;
    unsigned short* xb      = (unsigned short*)(ws + off); off += ND2;
    unsigned short* logitsb = (unsigned short*)(ws + off); off += ND2;
    unsigned short* featsb  = (unsigned short*)(ws + off); off += ND2;
    unsigned short* Wgb     = (unsigned short*)(ws + off); off += WD2;
    unsigned short* Wfb     = (unsigned short*)(ws + off); off += WD2;
    float* yv   = (float*)(ws + off); off += GD4;
    float* outg = (float*)(ws + off); off += GD4;
    int* counts  = (int*)(ws + off); off += (size_t)GG * 4;
    int* offsets = (int*)(ws + off); off += (size_t)(GG + 4) * 4;
    int* cursor  = (int*)(ws + off); off += (size_t)GG * 4;
    int* order   = (int*)(ws + off); off += (size_t)N * 4;

    hipMemsetAsync(counts, 0, (size_t)GG * 4, stream);
    hipMemsetAsync(cursor, 0, (size_t)GG * 4, stream);

    // Group-sort bookkeeping
    k_hist<<<N / 256, 256, 0, stream>>>(jx, counts, N);
    k_scan4096<<<1, 1024, 0, stream>>>(counts, offsets);
    k_scatter<<<N / 256, 256, 0, stream>>>(jx, offsets, cursor, order, N);

    // fp32 -> bf16 conversions
    k_f2b<<<(N * (DD / 4)) / 256, 256, 0, stream>>>(x, xb, N * (DD / 4));
    k_f2b<<<(DD * DD / 4) / 256, 256, 0, stream>>>(Wg, Wgb, DD * DD / 4);
    k_f2b<<<(DD * DD / 4) / 256, 256, 0, stream>>>(Wf, Wfb, DD * DD / 4);

    // logits = x@Wg^T + bg ; feats = x@Wf^T + bf   (bf16 MFMA, bf16 out)
    k_dual_gemm_mfma<<<GG, 256, 0, stream>>>(xb, Wgb, bg, Wfb, bf, logitsb, featsb);

    // per-group softmax-weighted sum (fp32 accumulate)
    k_group_agg<<<GG, 512, 0, stream>>>(logitsb, featsb, order, offsets, yv);

    // out_group = y@Wh^T + bh  (fp32, small)
    k_gemm_bt<<<dim3(DD / 64, GG / 64), 256, 0, stream>>>(yv, Wh, bh, outg);

    // out = out_group[jx]
    k_gather<<<(N * (DD / 4)) / 256, 256, 0, stream>>>(outg, jx, out);
}